// Round 7
// baseline (175.000 us; speedup 1.0000x reference)
//
#include <hip/hip_runtime.h>
#include <hip/hip_fp16.h>

#define BATCH   1024
#define IN      1024
#define OUT     40960
#define KF      7
#define BT      8            // batch rows per block: one 8-row fp16 table
#define NO      4            // output columns per thread
#define THREADS 256
#define OTILE   (THREADS * NO)   // 1024 outputs per block
#define CHUNKS  (OUT / 64)       // 640 chunks of 64 consecutive outputs

// Workspace layout (repacked once per launch by repack_kernel):
//   pmeta : uint2 [CHUNKS][KF][64]  {x = idx<<4 (LDS byte off), y = f32 val bits}
//   xpk   : f16   [BATCH/8][IN][8]  x rounded fp16, 8 batch rows per 16-B granule
#define PMETA_BYTES ((size_t)CHUNKS * KF * 64 * 8)        // 2,293,760
#define XPK_BYTES   ((size_t)(BATCH / 8) * IN * 8 * 2)    // 2,097,152

// Round-7 theory: all priceable pipes sum to ~48-52us (writes 26, LDS ~14,
// VALU 4-8, meta/stage ~6) but sparse_proj measures ~62-66us. The residual is
// invariant under instruction-mix and volume changes -> latency exposure at
// 5 blocks/CU (5 waves/SIMD). This version: BT=8 (16 KB LDS) +
// launch_bounds(256,8) -> 8 blocks/CU, 32 waves (1.6x TLP). Gather wave-instr
// count per CU is UNCHANGED (1 b128/record x 2x blocks); meta volume doubles
// (measured neutral, r4). Meta double-buffer dropped to fit 64 VGPR/wave.

__global__ __launch_bounds__(THREADS)
void repack_kernel(const float* __restrict__ x, const float* __restrict__ vals,
                   const int* __restrict__ idx,
                   uint2* __restrict__ pmeta, __half* __restrict__ xpk)
{
    const int gid = blockIdx.x * THREADS + threadIdx.x;
    if (blockIdx.x < 512) {
        // ---- part A: x[1024][1024] f32 -> xpk[g][i][8] f16 ----
        const int g = gid >> 10;        // batch group 0..127
        const int i = gid & 1023;       // column
        const float* xb = x + (size_t)g * 8 * IN + i;
        union { __half h[8]; float4 f; } u;
#pragma unroll
        for (int r = 0; r < 8; ++r) u.h[r] = __float2half_rn(xb[(size_t)r * IN]);
        *(float4*)&xpk[(size_t)gid * 8] = u.f;   // coalesced 16-B store
    } else {
        // ---- part B: idx/vals [OUT][KF] -> pmeta[CHUNKS][KF][64] ----
        const int t2 = gid - 512 * THREADS;      // 0 .. 286719
        const int c  = t2 / (KF * 64);
        const int r  = t2 % (KF * 64);
        const int k  = r >> 6;
        const int l  = r & 63;
        const size_t src = (size_t)(c * 64 + l) * KF + k;
        uint2 m;
        m.x = (unsigned)(idx[src] << 4);         // byte offset into xs table
        m.y = __float_as_uint(vals[src]);
        pmeta[t2] = m;
    }
}

__global__ __launch_bounds__(THREADS, 8)
void sparse_proj(const uint2* __restrict__ pmeta, const __half* __restrict__ xpk,
                 float* __restrict__ y)
{
    // one 8-row table: xs[i*16B] = rows b0 .. b0+7 (fp16)
    __shared__ __align__(16) __half xs[IN * 8];   // 16 KB -> 10 blocks LDS-max

    const int t     = threadIdx.x;
    const int b0    = blockIdx.y * BT;
    const int obase = blockIdx.x * OTILE + t;

    // ---- stage: straight 16 KB copy, already fp16 + gather-layout ----
    {
        const float4* src = (const float4*)(xpk + (size_t)blockIdx.y * IN * 8);
        float4* dst = (float4*)xs;
#pragma unroll
        for (int r = 0; r < 4; ++r) dst[t + r * THREADS] = src[t + r * THREADS];
    }
    __syncthreads();

    const int w    = t >> 6;
    const int lane = t & 63;

    // Group no's chunk: c = blockIdx.x*16 + no*4 + w.
    // Record offset from mbase (in uint2): no * 4 * (KF*64) + k*64.
    const uint2* mbase = pmeta + (size_t)(blockIdx.x * 16 + w) * (KF * 64) + lane;

#pragma unroll
    for (int no = 0; no < NO; ++no) {
        // ---- meta for this group: 7 coalesced dwordx2 loads ----
        uint2 mc[KF];
#pragma unroll
        for (int k = 0; k < KF; ++k)
            mc[k] = mbase[(size_t)no * 4 * (KF * 64) + k * 64];

        float acc[BT];
#pragma unroll
        for (int r = 0; r < BT; ++r) acc[r] = 0.0f;

#pragma unroll
        for (int k = 0; k < KF; ++k) {
            const unsigned off = mc[k].x;            // i*16
            const float v = __uint_as_float(mc[k].y);
            const float4 g0 = *(const float4*)((const char*)xs + off); // 8 rows
            const __half2 a0 = *(const __half2*)&g0.x;
            const __half2 a1 = *(const __half2*)&g0.y;
            const __half2 a2 = *(const __half2*)&g0.z;
            const __half2 a3 = *(const __half2*)&g0.w;
            acc[0] = fmaf(v, __low2float(a0),  acc[0]);
            acc[1] = fmaf(v, __high2float(a0), acc[1]);
            acc[2] = fmaf(v, __low2float(a1),  acc[2]);
            acc[3] = fmaf(v, __high2float(a1), acc[3]);
            acc[4] = fmaf(v, __low2float(a2),  acc[4]);
            acc[5] = fmaf(v, __high2float(a2), acc[5]);
            acc[6] = fmaf(v, __low2float(a3),  acc[6]);
            acc[7] = fmaf(v, __high2float(a3), acc[7]);
        }

        // ---- store this group now (plain stores: retire at L2). 256 B per
        // wave per row, coalesced. ----
        const int o = obase + no * THREADS;
#pragma unroll
        for (int r = 0; r < BT; ++r) {
            y[(size_t)(b0 + r) * OUT + o] = acc[r];
        }
    }
}

extern "C" void kernel_launch(void* const* d_in, const int* in_sizes, int n_in,
                              void* d_out, int out_size, void* d_ws, size_t ws_size,
                              hipStream_t stream) {
    const float* x    = (const float*)d_in[0];   // [1024, 1024] fp32
    const float* vals = (const float*)d_in[1];   // [40960, 7]  fp32
    const int*   idx  = (const int*)d_in[2];     // [40960, 7]  int32
    float*       y    = (float*)d_out;           // [1024, 40960] fp32

    uint2*  pmeta = (uint2*)d_ws;
    __half* xpk   = (__half*)((char*)d_ws + PMETA_BYTES);

    // 512 blocks for xpk (131072 threads) + 1120 blocks for pmeta (286720)
    repack_kernel<<<dim3(512 + 1120), dim3(THREADS), 0, stream>>>(
        x, vals, idx, pmeta, xpk);

    dim3 grid(OUT / OTILE, BATCH / BT);          // (40, 128) = 5120 blocks
    sparse_proj<<<grid, dim3(THREADS), 0, stream>>>(pmeta, xpk, y);
}